// Round 3
// baseline (248.748 us; speedup 1.0000x reference)
//
#include <hip/hip_runtime.h>
#include <cstddef>
#include <cstdint>

#define BB 4
#define TT 2048
#define CC 1024
#define LL 256
#define HH 16
#define DD 64   // head size
#define QLD (CC + LL)  // 1280: row stride of fused q|latent buffer

typedef __attribute__((ext_vector_type(8))) short s16x8;
typedef __attribute__((ext_vector_type(4))) float f32x4;

static __device__ inline unsigned short f2bf(float f) {
    union { float f; unsigned u; } v; v.f = f;
    unsigned r = v.u + 0x7fffu + ((v.u >> 16) & 1u);  // RNE
    return (unsigned short)(r >> 16);
}

static __device__ inline float fast_exp2(float x) {
#if __has_builtin(__builtin_amdgcn_exp2f)
    return __builtin_amdgcn_exp2f(x);
#else
    return exp2f(x);
#endif
}

// pack two f32 -> two bf16 (truncation) in one v_perm_b32; lo -> low 16 bits
static __device__ inline unsigned pack_bf16_trunc(float lo, float hi) {
    union { float f; unsigned u; } a, b;
    a.f = lo; b.f = hi;
    return __builtin_amdgcn_perm(b.u, a.u, 0x07060302u);
}

// async global->LDS, 16B per lane; LDS dest = wave-uniform base + lane*16
#define GLDS16(g, l)                                             \
    __builtin_amdgcn_global_load_lds(                            \
        (__attribute__((address_space(1))) void*)(g),            \
        (__attribute__((address_space(3))) void*)(l), 16, 0, 0)

// ====================== fused conversion kernel =============================
// blocks [0, 8192): x fp32 -> bf16 (1024 elems/block)
// blocks [8192, 8896): one 64x64 transpose tile of a weight matrix
extern "C" __global__ __launch_bounds__(256)
void fused_cvt(const float* __restrict__ x, unsigned short* __restrict__ xb,
               const float* __restrict__ Wq, const float* __restrict__ Wkv,
               const float* __restrict__ Wk, const float* __restrict__ Wv,
               const float* __restrict__ Wo,
               unsigned short* __restrict__ W1t, unsigned short* __restrict__ W2t,
               unsigned short* __restrict__ Wot, float qscale) {
    __shared__ unsigned short Ts[64][72];
    const int t = threadIdx.x;
    int blk = blockIdx.x;
    if (blk < 8192) {
        const int i = blk * 256 + t;
        const float4 v = ((const float4*)x)[i];
        ushort4 o;
        o.x = f2bf(v.x); o.y = f2bf(v.y); o.z = f2bf(v.z); o.w = f2bf(v.w);
        ((ushort4*)xb)[i] = o;
        return;
    }
    blk -= 8192;
    const float* W; unsigned short* Wt; int K, N; float scale; int tile;
    if (blk < 256)      { W = Wq;  Wt = W1t;                      K = CC; N = CC; scale = qscale; tile = blk; }
    else if (blk < 320) { W = Wkv; Wt = W1t + (size_t)CC * CC;    K = CC; N = LL; scale = 1.f;    tile = blk - 256; }
    else if (blk < 384) { W = Wk;  Wt = W2t;                      K = LL; N = CC; scale = 1.f;    tile = blk - 320; }
    else if (blk < 448) { W = Wv;  Wt = W2t + (size_t)CC * LL;    K = LL; N = CC; scale = 1.f;    tile = blk - 384; }
    else                { W = Wo;  Wt = Wot;                      K = CC; N = CC; scale = 1.f;    tile = blk - 448; }
    const int ktiles = K >> 6;
    const int k0 = (tile % ktiles) * 64, n0 = (tile / ktiles) * 64;
#pragma unroll
    for (int l = 0; l < 4; ++l) {
        const int idx = t + l * 256;
        const int r = idx >> 4, c4 = (idx & 15) * 4;
        const float4 v = *(const float4*)(W + (size_t)(k0 + r) * N + n0 + c4);
        Ts[c4 + 0][r] = f2bf(v.x * scale); Ts[c4 + 1][r] = f2bf(v.y * scale);
        Ts[c4 + 2][r] = f2bf(v.z * scale); Ts[c4 + 3][r] = f2bf(v.w * scale);
    }
    __syncthreads();
#pragma unroll
    for (int l = 0; l < 2; ++l) {
        const int idx = t + l * 256;
        const int n = idx >> 3, seg = idx & 7;
        *(s16x8*)(Wt + (size_t)(n0 + n) * K + k0 + seg * 8) = *(const s16x8*)&Ts[n][seg * 8];
    }
}

// ========== bf16 MFMA GEMM: C[M,N] = A[M,K] @ Bt[N,K]^T ====================
// 128x128 tile, BK=64, 256 threads = 4 waves (2x2), 4x4 16x16x32 MFMA per wave.
// Staging via global_load_lds with XOR source swizzle: LDS[row][s] holds global
// segment s^(row&7)  ->  fragment ds_read_b128 is 2-way banked (free, m136).
// MODE 0: fp32 store (ldc) | MODE 1: bf16 store (ldc)
// MODE 3: cols < CC -> bf16 store (ldc); cols >= CC -> transposed vt store
template <int MODE>
__global__ __launch_bounds__(256)
void bgemm(const unsigned short* __restrict__ A, const unsigned short* __restrict__ Bt,
           void* __restrict__ Cv, void* __restrict__ Cv2,
           int M, int N, int K, int lda, int ldc) {
    __shared__ unsigned short As[128][64];
    __shared__ unsigned short Bs[128][64];
    const int t = threadIdx.x;
    const int w = t >> 6, lane = t & 63, quad = lane >> 4, l16 = lane & 15;
    const int wm = w & 1, wn = w >> 1;
    const int row0 = blockIdx.y * 128, col0 = blockIdx.x * 128;
    const int sr = lane >> 3;                 // row within an 8-row chunk
    const int sc = ((lane & 7) ^ sr) * 8;     // swizzled 16B source segment

    f32x4 acc[4][4];
#pragma unroll
    for (int i = 0; i < 4; ++i)
#pragma unroll
        for (int j = 0; j < 4; ++j) acc[i][j] = (f32x4){0.f, 0.f, 0.f, 0.f};

    const unsigned short* Ab = A + (size_t)(row0 + w * 32 + sr) * lda + sc;
    const unsigned short* Bb = Bt + (size_t)(col0 + w * 32 + sr) * K + sc;

    for (int k0 = 0; k0 < K; k0 += 64) {
#pragma unroll
        for (int c = 0; c < 4; ++c) {
            GLDS16(Ab + (size_t)(c * 8) * lda + k0, &As[w * 32 + c * 8][0]);
            GLDS16(Bb + (size_t)(c * 8) * K + k0, &Bs[w * 32 + c * 8][0]);
        }
        __syncthreads();
#pragma unroll
        for (int kk = 0; kk < 2; ++kk) {
            s16x8 af[4], bfr[4];
#pragma unroll
            for (int mt = 0; mt < 4; ++mt)
                af[mt] = *(const s16x8*)
                    &As[wm * 64 + mt * 16 + l16][((kk * 4 + quad) ^ (l16 & 7)) * 8];
#pragma unroll
            for (int nt = 0; nt < 4; ++nt)
                bfr[nt] = *(const s16x8*)
                    &Bs[wn * 64 + nt * 16 + l16][((kk * 4 + quad) ^ (l16 & 7)) * 8];
#pragma unroll
            for (int mt = 0; mt < 4; ++mt)
#pragma unroll
                for (int nt = 0; nt < 4; ++nt)
                    acc[mt][nt] = __builtin_amdgcn_mfma_f32_16x16x32_bf16(
                        af[mt], bfr[nt], acc[mt][nt], 0, 0, 0);
        }
        __syncthreads();
    }

    if constexpr (MODE == 0) {
        float* C = (float*)Cv;
#pragma unroll
        for (int mt = 0; mt < 4; ++mt)
#pragma unroll
            for (int nt = 0; nt < 4; ++nt)
#pragma unroll
                for (int r = 0; r < 4; ++r)
                    C[(size_t)(row0 + wm * 64 + mt * 16 + quad * 4 + r) * ldc +
                      col0 + wn * 64 + nt * 16 + l16] = acc[mt][nt][r];
    } else if constexpr (MODE == 1) {
        unsigned short* C = (unsigned short*)Cv;
#pragma unroll
        for (int mt = 0; mt < 4; ++mt)
#pragma unroll
            for (int nt = 0; nt < 4; ++nt)
#pragma unroll
                for (int r = 0; r < 4; ++r)
                    C[(size_t)(row0 + wm * 64 + mt * 16 + quad * 4 + r) * ldc +
                      col0 + wn * 64 + nt * 16 + l16] = f2bf(acc[mt][nt][r]);
    } else {
        if (col0 < CC) {
            unsigned short* C = (unsigned short*)Cv;
#pragma unroll
            for (int mt = 0; mt < 4; ++mt)
#pragma unroll
                for (int nt = 0; nt < 4; ++nt)
#pragma unroll
                    for (int r = 0; r < 4; ++r)
                        C[(size_t)(row0 + wm * 64 + mt * 16 + quad * 4 + r) * ldc +
                          col0 + wn * 64 + nt * 16 + l16] = f2bf(acc[mt][nt][r]);
        } else {
            // v-half: transposed store vt[b][h][dv][t]
            __shared__ unsigned short Tb[64][136];
            unsigned short* vt = (unsigned short*)Cv2;
            const int b   = row0 >> 11;  // 2048 tokens per batch; tile never crosses
            const int tl0 = row0 & 2047;
#pragma unroll
            for (int h = 0; h < 2; ++h) {
                if (wn == h) {
#pragma unroll
                    for (int mt = 0; mt < 4; ++mt)
#pragma unroll
                        for (int nt = 0; nt < 4; ++nt)
#pragma unroll
                            for (int r = 0; r < 4; ++r)
                                Tb[nt * 16 + l16][wm * 64 + mt * 16 + quad * 4 + r] =
                                    f2bf(acc[mt][nt][r]);
                }
                __syncthreads();
                const int head = ((col0 - CC) >> 6) + h;
#pragma unroll
                for (int l = 0; l < 4; ++l) {
                    const int idx = t + l * 256;
                    const int dv = idx >> 4, seg = idx & 15;
                    *(s16x8*)(vt + (((size_t)b * HH + head) * DD + dv) * TT + tl0 + seg * 8) =
                        *(const s16x8*)&Tb[dv][seg * 8];
                }
                __syncthreads();
            }
        }
    }
}

// ================= Flash attention v3: KVBLK=128, single buffer =============
// grid (B*H, TT/128) with qt2 REVERSED (heaviest blocks dispatch first).
// 256 threads = 4 waves; wave w owns 32 queries.
// q: bf16 [b][t][QLD] (q|latent fused, pre-scaled by 0.125*log2(e));
// k: bf16 [b][t][h*64+d]; vt: bf16 [b][h][dv][t]; y: bf16 [b][t][c].
//
// Round 3 change: the null results of r1 (dbuf) and r2 (reg-P) showed the
// kernel is bound by the COUNT of barrier-synchronized serial steps, not by
// issue work. KVBLK goes 64 -> 128 (two 64-key halves computed inside one
// barrier window, no barrier between halves): serial steps and barrier count
// halve (critical block: 32 -> 16 steps). Single-buffered: Ks[128][64] +
// Vs[64][128] = 32 KB -> still 4 blocks/CU. P stays fully in registers
// (permlane redistribution, r2). s_setprio(1) wraps compute (T5, +4-7% attn).
extern "C" __global__ __launch_bounds__(256, 4)
void mla_attn2(const unsigned short* __restrict__ q,
               const unsigned short* __restrict__ k,
               const unsigned short* __restrict__ vt,
               unsigned short* __restrict__ y) {
    __shared__ unsigned short Ks[128][64];  // [key][d], source-XOR-swizzled segs
    __shared__ unsigned short Vs[64][128];  // [dv][key], source-XOR-swizzled segs

    const int bh = blockIdx.x;
    const int qt2 = (gridDim.y - 1) - blockIdx.y;  // big blocks first (LPT packing)
    const int b = bh >> 4, h = bh & 15;
    const int t0 = qt2 * 128;
    const int t = threadIdx.x;
    const int w = t >> 6, lane = t & 63, quad = lane >> 4, l16 = lane & 15;
    const int qw0 = t0 + w * 32;                       // wave's first query
    const int lrow8 = lane >> 3;                       // row within 8-row K chunk
    const int swzk = ((lane & 7) ^ lrow8) * 8;         // K swizzled source seg (elems)

    const unsigned short* kb0 = k + ((size_t)b * TT) * CC + h * DD;
    const unsigned short* vb0 = vt + ((size_t)(b * HH + h)) * DD * TT;

    // Q fragments straight from global (pre-scaled), hoisted
    s16x8 qf[2][2];
#pragma unroll
    for (int qs = 0; qs < 2; ++qs)
#pragma unroll
        for (int kh = 0; kh < 2; ++kh)
            qf[qs][kh] = *(const s16x8*)(q + ((size_t)b * TT + qw0 + qs * 16 + l16) * QLD +
                                         h * DD + kh * 32 + quad * 8);

    f32x4 o[2][4];
    float lsum[2] = {0.f, 0.f};
#pragma unroll
    for (int qs = 0; qs < 2; ++qs)
#pragma unroll
        for (int nt = 0; nt < 4; ++nt) o[qs][nt] = (f32x4){0.f, 0.f, 0.f, 0.f};

    const int nkt = qt2 + 1;  // 128-key tiles
    for (int kt = 0; kt < nkt; ++kt) {
        const int s0 = kt * 128;
        // ---- stage K[128][64] and V[64][128] (16 KB each), 8 GLDS16/wave ----
#pragma unroll
        for (int c = 0; c < 4; ++c) {
            const int g = w * 4 + c;  // K chunk: 8 rows x 128B
            GLDS16(kb0 + (size_t)(s0 + g * 8 + lrow8) * CC + swzk, &Ks[g * 8][0]);
        }
#pragma unroll
        for (int c = 0; c < 4; ++c) {
            const int g = w * 4 + c;  // V chunk: 4 rows x 256B
            const int row = g * 4 + (lane >> 4);
            const int ss = ((lane & 15) ^ (row & 7)) * 8;  // swizzled source seg
            GLDS16(vb0 + (size_t)row * TT + s0 + ss, &Vs[g * 4][0]);
        }
        __syncthreads();  // vmcnt(0) drain + barrier: tile staged

        __builtin_amdgcn_s_setprio(1);
#pragma unroll
        for (int hf = 0; hf < 2; ++hf) {
            const int h0 = s0 + hf * 64;
            if (h0 <= qw0 + 31) {  // wave-uniform: any unmasked key in this half?
                // S^T = K Q^T : A=K[m=key], B=Q^T[k=d][n=q]; D row=key, col=q
                f32x4 st[2][4];
#pragma unroll
                for (int nt = 0; nt < 4; ++nt) {
                    const int key = hf * 64 + nt * 16 + l16;
                    const s16x8 kf0 = *(const s16x8*)&Ks[key][((0 + quad) ^ (l16 & 7)) * 8];
                    const s16x8 kf1 = *(const s16x8*)&Ks[key][((4 + quad) ^ (l16 & 7)) * 8];
#pragma unroll
                    for (int qs = 0; qs < 2; ++qs) {
                        f32x4 acc = (f32x4){0.f, 0.f, 0.f, 0.f};
                        acc = __builtin_amdgcn_mfma_f32_16x16x32_bf16(kf0, qf[qs][0], acc, 0, 0, 0);
                        acc = __builtin_amdgcn_mfma_f32_16x16x32_bf16(kf1, qf[qs][1], acc, 0, 0, 0);
                        st[qs][nt] = acc;
                    }
                }

                const bool maskedHalf = (h0 + 63 > qw0);  // wave-uniform
                s16x8 pf[2][2];
#pragma unroll
                for (int qs = 0; qs < 2; ++qs) {
                    const int qidx = qw0 + qs * 16 + l16;
                    unsigned pc[4][2];
                    float tsum = 0.f;
#pragma unroll
                    for (int nt = 0; nt < 4; ++nt) {
                        const int key0 = h0 + nt * 16 + quad * 4;
                        float p[4];
#pragma unroll
                        for (int r = 0; r < 4; ++r) {
                            float sv = st[qs][nt][r];
                            if (maskedHalf && (key0 + r > qidx)) sv = -1e30f;
                            p[r] = fast_exp2(sv);
                        }
                        tsum += (p[0] + p[1]) + (p[2] + p[3]);  // tree, short dep chain
                        pc[nt][0] = pack_bf16_trunc(p[0], p[1]);
                        pc[nt][1] = pack_bf16_trunc(p[2], p[3]);
                    }
                    lsum[qs] += tsum;
                    // in-register P redistribution: quads exchange via permlane swaps
#pragma unroll
                    for (int kh = 0; kh < 2; ++kh) {
                        auto s0a = __builtin_amdgcn_permlane32_swap(
                            (int)pc[2 * kh + 0][0], (int)pc[2 * kh + 1][0], false, false);
                        auto w02 = __builtin_amdgcn_permlane16_swap(s0a[0], s0a[1], false, false);
                        auto s1a = __builtin_amdgcn_permlane32_swap(
                            (int)pc[2 * kh + 0][1], (int)pc[2 * kh + 1][1], false, false);
                        auto w13 = __builtin_amdgcn_permlane16_swap(s1a[0], s1a[1], false, false);
                        union { unsigned u[4]; s16x8 v; } fu;
                        fu.u[0] = (unsigned)w02[0];  // keys +0,+1
                        fu.u[1] = (unsigned)w13[0];  // keys +2,+3
                        fu.u[2] = (unsigned)w02[1];  // keys +4,+5
                        fu.u[3] = (unsigned)w13[1];  // keys +6,+7
                        pf[qs][kh] = fu.v;
                    }
                }

                // PV: A=P[m=q][k=key] in registers; B=V[k=key][n=dv] from Vs rows
#pragma unroll
                for (int nt = 0; nt < 4; ++nt) {
                    const int dv = nt * 16 + l16;
                    const s16x8 vf0 = *(const s16x8*)
                        &Vs[dv][((hf << 3) | ((0 + quad) ^ (l16 & 7))) * 8];
                    const s16x8 vf1 = *(const s16x8*)
                        &Vs[dv][((hf << 3) | ((4 + quad) ^ (l16 & 7))) * 8];
#pragma unroll
                    for (int qs = 0; qs < 2; ++qs) {
                        o[qs][nt] = __builtin_amdgcn_mfma_f32_16x16x32_bf16(pf[qs][0], vf0,
                                                                            o[qs][nt], 0, 0, 0);
                        o[qs][nt] = __builtin_amdgcn_mfma_f32_16x16x32_bf16(pf[qs][1], vf1,
                                                                            o[qs][nt], 0, 0, 0);
                    }
                }
            }
        }
        __builtin_amdgcn_s_setprio(0);
        __syncthreads();  // all waves done reading before next stage overwrites
    }

    // final l reduction: quads hold partial sums for query qs*16+l16
    float lfull[2];
#pragma unroll
    for (int qs = 0; qs < 2; ++qs) {
        float s = lsum[qs];
        s += __shfl_xor(s, 16);
        s += __shfl_xor(s, 32);
        lfull[qs] = s;
    }

    // store: o element = (query qs*16+quad*4+r, dv nt*16+l16)
#pragma unroll
    for (int qs = 0; qs < 2; ++qs) {
#pragma unroll
        for (int r = 0; r < 4; ++r) {
            const float inv = 1.f / __shfl(lfull[qs], quad * 4 + r);
            unsigned short* yb = y + ((size_t)b * TT + qw0 + qs * 16 + quad * 4 + r) * CC +
                                 h * DD + l16;
#pragma unroll
            for (int nt = 0; nt < 4; ++nt)
                yb[nt * 16] = f2bf(o[qs][nt][r] * inv);
        }
    }
}

extern "C" void kernel_launch(void* const* d_in, const int* in_sizes, int n_in,
                              void* d_out, int out_size, void* d_ws, size_t ws_size,
                              hipStream_t stream) {
    const float* x   = (const float*)d_in[0];
    const float* Wq  = (const float*)d_in[1];
    const float* Wkv = (const float*)d_in[2];
    const float* Wk  = (const float*)d_in[3];
    const float* Wv  = (const float*)d_in[4];
    const float* Wo  = (const float*)d_in[5];
    float* out = (float*)d_out;

    const int M = BB * TT;  // 8192
    unsigned short* p = (unsigned short*)d_ws;
    unsigned short* xb    = p; p += (size_t)M * CC;     // bf16 x
    unsigned short* qlatb = p; p += (size_t)M * QLD;    // fused q | latent
    unsigned short* kb    = p; p += (size_t)M * CC;
    unsigned short* vtb   = p; p += (size_t)M * CC;
    unsigned short* yb    = p; p += (size_t)M * CC;
    unsigned short* W1t   = p; p += (size_t)QLD * CC;   // [Wq^T ; Wkv^T]  [1280][1024]
    unsigned short* W2t   = p; p += (size_t)(2 * CC) * LL;  // [Wk^T ; Wv^T] [2048][256]
    unsigned short* Wot   = p; p += (size_t)CC * CC;

    const float qscale = 0.125f * 1.44269504f;  // 1/sqrt(64) * log2(e), folded into Wq

    fused_cvt<<<8896, 256, 0, stream>>>(x, xb, Wq, Wkv, Wk, Wv, Wo,
                                        W1t, W2t, Wot, qscale);
    // fused q|latent projection: [M,1280] = x @ [Wq | Wkv]
    bgemm<1><<<dim3(QLD / 128, M / 128), 256, 0, stream>>>(
        xb, W1t, qlatb, nullptr, M, QLD, CC, CC, QLD);
    // fused k|v up-projection: k half -> kb, v half -> vtb (transposed)
    bgemm<3><<<dim3(2 * CC / 128, M / 128), 256, 0, stream>>>(
        qlatb + CC, W2t, kb, vtb, M, 2 * CC, LL, QLD, CC);
    mla_attn2<<<dim3(BB * HH, TT / 128), 256, 0, stream>>>(qlatb, kb, vtb, yb);
    bgemm<0><<<dim3(CC / 128, M / 128), 256, 0, stream>>>(
        yb, Wot, out, nullptr, M, CC, CC, CC, CC);
}

// Round 4
// 245.243 us; speedup vs baseline: 1.0143x; 1.0143x over previous
//
#include <hip/hip_runtime.h>
#include <cstddef>
#include <cstdint>

#define BB 4
#define TT 2048
#define CC 1024
#define LL 256
#define HH 16
#define DD 64   // head size
#define QLD (CC + LL)  // 1280: row stride of fused q|latent buffer

typedef __attribute__((ext_vector_type(8))) short s16x8;
typedef __attribute__((ext_vector_type(4))) float f32x4;

static __device__ inline unsigned short f2bf(float f) {
    union { float f; unsigned u; } v; v.f = f;
    unsigned r = v.u + 0x7fffu + ((v.u >> 16) & 1u);  // RNE
    return (unsigned short)(r >> 16);
}

static __device__ inline float fast_exp2(float x) {
#if __has_builtin(__builtin_amdgcn_exp2f)
    return __builtin_amdgcn_exp2f(x);
#else
    return exp2f(x);
#endif
}

// pack two f32 -> two bf16 (truncation) in one v_perm_b32; lo -> low 16 bits
static __device__ inline unsigned pack_bf16_trunc(float lo, float hi) {
    union { float f; unsigned u; } a, b;
    a.f = lo; b.f = hi;
    return __builtin_amdgcn_perm(b.u, a.u, 0x07060302u);
}

// async global->LDS, 16B per lane; LDS dest = wave-uniform base + lane*16
#define GLDS16(g, l)                                             \
    __builtin_amdgcn_global_load_lds(                            \
        (__attribute__((address_space(1))) void*)(g),            \
        (__attribute__((address_space(3))) void*)(l), 16, 0, 0)

// ====================== fused conversion kernel =============================
// blocks [0, 8192): x fp32 -> bf16 (1024 elems/block)
// blocks [8192, 8896): one 64x64 transpose tile of a weight matrix
extern "C" __global__ __launch_bounds__(256)
void fused_cvt(const float* __restrict__ x, unsigned short* __restrict__ xb,
               const float* __restrict__ Wq, const float* __restrict__ Wkv,
               const float* __restrict__ Wk, const float* __restrict__ Wv,
               const float* __restrict__ Wo,
               unsigned short* __restrict__ W1t, unsigned short* __restrict__ W2t,
               unsigned short* __restrict__ Wot, float qscale) {
    __shared__ unsigned short Ts[64][72];
    const int t = threadIdx.x;
    int blk = blockIdx.x;
    if (blk < 8192) {
        const int i = blk * 256 + t;
        const float4 v = ((const float4*)x)[i];
        ushort4 o;
        o.x = f2bf(v.x); o.y = f2bf(v.y); o.z = f2bf(v.z); o.w = f2bf(v.w);
        ((ushort4*)xb)[i] = o;
        return;
    }
    blk -= 8192;
    const float* W; unsigned short* Wt; int K, N; float scale; int tile;
    if (blk < 256)      { W = Wq;  Wt = W1t;                      K = CC; N = CC; scale = qscale; tile = blk; }
    else if (blk < 320) { W = Wkv; Wt = W1t + (size_t)CC * CC;    K = CC; N = LL; scale = 1.f;    tile = blk - 256; }
    else if (blk < 384) { W = Wk;  Wt = W2t;                      K = LL; N = CC; scale = 1.f;    tile = blk - 320; }
    else if (blk < 448) { W = Wv;  Wt = W2t + (size_t)CC * LL;    K = LL; N = CC; scale = 1.f;    tile = blk - 384; }
    else                { W = Wo;  Wt = Wot;                      K = CC; N = CC; scale = 1.f;    tile = blk - 448; }
    const int ktiles = K >> 6;
    const int k0 = (tile % ktiles) * 64, n0 = (tile / ktiles) * 64;
#pragma unroll
    for (int l = 0; l < 4; ++l) {
        const int idx = t + l * 256;
        const int r = idx >> 4, c4 = (idx & 15) * 4;
        const float4 v = *(const float4*)(W + (size_t)(k0 + r) * N + n0 + c4);
        Ts[c4 + 0][r] = f2bf(v.x * scale); Ts[c4 + 1][r] = f2bf(v.y * scale);
        Ts[c4 + 2][r] = f2bf(v.z * scale); Ts[c4 + 3][r] = f2bf(v.w * scale);
    }
    __syncthreads();
#pragma unroll
    for (int l = 0; l < 2; ++l) {
        const int idx = t + l * 256;
        const int n = idx >> 3, seg = idx & 7;
        *(s16x8*)(Wt + (size_t)(n0 + n) * K + k0 + seg * 8) = *(const s16x8*)&Ts[n][seg * 8];
    }
}

// ========== bf16 MFMA GEMM: C[M,N] = A[M,K] @ Bt[N,K]^T ====================
// 128x128 tile, BK=64, 256 threads = 4 waves (2x2), 4x4 16x16x32 MFMA per wave.
// Staging via global_load_lds with XOR source swizzle: LDS[row][s] holds global
// segment s^(row&7)  ->  fragment ds_read_b128 is 2-way banked (free, m136).
// MODE 0: fp32 store (ldc) | MODE 1: bf16 store (ldc)
// MODE 3: cols < CC -> bf16 store (ldc); cols >= CC -> transposed vt store
template <int MODE>
__global__ __launch_bounds__(256)
void bgemm(const unsigned short* __restrict__ A, const unsigned short* __restrict__ Bt,
           void* __restrict__ Cv, void* __restrict__ Cv2,
           int M, int N, int K, int lda, int ldc) {
    __shared__ unsigned short As[128][64];
    __shared__ unsigned short Bs[128][64];
    const int t = threadIdx.x;
    const int w = t >> 6, lane = t & 63, quad = lane >> 4, l16 = lane & 15;
    const int wm = w & 1, wn = w >> 1;
    const int row0 = blockIdx.y * 128, col0 = blockIdx.x * 128;
    const int sr = lane >> 3;                 // row within an 8-row chunk
    const int sc = ((lane & 7) ^ sr) * 8;     // swizzled 16B source segment

    f32x4 acc[4][4];
#pragma unroll
    for (int i = 0; i < 4; ++i)
#pragma unroll
        for (int j = 0; j < 4; ++j) acc[i][j] = (f32x4){0.f, 0.f, 0.f, 0.f};

    const unsigned short* Ab = A + (size_t)(row0 + w * 32 + sr) * lda + sc;
    const unsigned short* Bb = Bt + (size_t)(col0 + w * 32 + sr) * K + sc;

    for (int k0 = 0; k0 < K; k0 += 64) {
#pragma unroll
        for (int c = 0; c < 4; ++c) {
            GLDS16(Ab + (size_t)(c * 8) * lda + k0, &As[w * 32 + c * 8][0]);
            GLDS16(Bb + (size_t)(c * 8) * K + k0, &Bs[w * 32 + c * 8][0]);
        }
        __syncthreads();
#pragma unroll
        for (int kk = 0; kk < 2; ++kk) {
            s16x8 af[4], bfr[4];
#pragma unroll
            for (int mt = 0; mt < 4; ++mt)
                af[mt] = *(const s16x8*)
                    &As[wm * 64 + mt * 16 + l16][((kk * 4 + quad) ^ (l16 & 7)) * 8];
#pragma unroll
            for (int nt = 0; nt < 4; ++nt)
                bfr[nt] = *(const s16x8*)
                    &Bs[wn * 64 + nt * 16 + l16][((kk * 4 + quad) ^ (l16 & 7)) * 8];
#pragma unroll
            for (int mt = 0; mt < 4; ++mt)
#pragma unroll
                for (int nt = 0; nt < 4; ++nt)
                    acc[mt][nt] = __builtin_amdgcn_mfma_f32_16x16x32_bf16(
                        af[mt], bfr[nt], acc[mt][nt], 0, 0, 0);
        }
        __syncthreads();
    }

    if constexpr (MODE == 0) {
        float* C = (float*)Cv;
#pragma unroll
        for (int mt = 0; mt < 4; ++mt)
#pragma unroll
            for (int nt = 0; nt < 4; ++nt)
#pragma unroll
                for (int r = 0; r < 4; ++r)
                    C[(size_t)(row0 + wm * 64 + mt * 16 + quad * 4 + r) * ldc +
                      col0 + wn * 64 + nt * 16 + l16] = acc[mt][nt][r];
    } else if constexpr (MODE == 1) {
        unsigned short* C = (unsigned short*)Cv;
#pragma unroll
        for (int mt = 0; mt < 4; ++mt)
#pragma unroll
            for (int nt = 0; nt < 4; ++nt)
#pragma unroll
                for (int r = 0; r < 4; ++r)
                    C[(size_t)(row0 + wm * 64 + mt * 16 + quad * 4 + r) * ldc +
                      col0 + wn * 64 + nt * 16 + l16] = f2bf(acc[mt][nt][r]);
    } else {
        if (col0 < CC) {
            unsigned short* C = (unsigned short*)Cv;
#pragma unroll
            for (int mt = 0; mt < 4; ++mt)
#pragma unroll
                for (int nt = 0; nt < 4; ++nt)
#pragma unroll
                    for (int r = 0; r < 4; ++r)
                        C[(size_t)(row0 + wm * 64 + mt * 16 + quad * 4 + r) * ldc +
                          col0 + wn * 64 + nt * 16 + l16] = f2bf(acc[mt][nt][r]);
        } else {
            // v-half: transposed store vt[b][h][dv][t]
            __shared__ unsigned short Tb[64][136];
            unsigned short* vt = (unsigned short*)Cv2;
            const int b   = row0 >> 11;  // 2048 tokens per batch; tile never crosses
            const int tl0 = row0 & 2047;
#pragma unroll
            for (int h = 0; h < 2; ++h) {
                if (wn == h) {
#pragma unroll
                    for (int mt = 0; mt < 4; ++mt)
#pragma unroll
                        for (int nt = 0; nt < 4; ++nt)
#pragma unroll
                            for (int r = 0; r < 4; ++r)
                                Tb[nt * 16 + l16][wm * 64 + mt * 16 + quad * 4 + r] =
                                    f2bf(acc[mt][nt][r]);
                }
                __syncthreads();
                const int head = ((col0 - CC) >> 6) + h;
#pragma unroll
                for (int l = 0; l < 4; ++l) {
                    const int idx = t + l * 256;
                    const int dv = idx >> 4, seg = idx & 15;
                    *(s16x8*)(vt + (((size_t)b * HH + head) * DD + dv) * TT + tl0 + seg * 8) =
                        *(const s16x8*)&Tb[dv][seg * 8];
                }
                __syncthreads();
            }
        }
    }
}

// ================= Flash attention v4: 1-wave blocks, no LDS, no barriers ===
// Post-mortem r0-r3: the 4-wave barrier-periodic structure convoy-locks all
// co-resident blocks (identical code, simultaneous start) -> per-step wall
// time ~4x the critical path, insensitive to issue-work changes (r2) and
// worse with longer phases (r3). This version deletes ALL synchronization:
// one wave per block, 64 queries per wave, K/V MFMA fragments loaded DIRECTLY
// from global (both are 16B-contiguous in the existing layouts):
//   K frag:  k[b][s0+nt*16+l16][h*64 + kh*32+quad*8 ..+7]   (contig in d)
//   V frag:  vt[b][h][nt*16+l16][s0 + kh*32+quad*8 ..+7]    (contig in key)
// P stays fully in registers (r2's verified permlane dance). K/V redundancy
// is 4x vs LDS sharing (~540 MB total, L2-resident), far under per-XCD L2 BW.
// grid (B*H, TT/64) with qt REVERSED (heaviest blocks first, LPT).
extern "C" __global__ __launch_bounds__(64, 2)
void mla_attn3(const unsigned short* __restrict__ q,
               const unsigned short* __restrict__ k,
               const unsigned short* __restrict__ vt,
               unsigned short* __restrict__ y) {
    const int bh = blockIdx.x;
    const int qt = (gridDim.y - 1) - blockIdx.y;  // big blocks first
    const int b = bh >> 4, h = bh & 15;
    const int qw0 = qt * 64;
    const int lane = threadIdx.x & 63;
    const int quad = lane >> 4, l16 = lane & 15;

    // per-lane base pointers (16B-aligned fragment starts)
    const unsigned short* kb = k + ((size_t)b * TT) * CC + h * DD + quad * 8;
    const unsigned short* vb = vt + ((size_t)(b * HH + h)) * DD * TT + quad * 8;

    // Q fragments (pre-scaled by 0.125*log2(e) via Wq), hoisted
    s16x8 qf[4][2];
#pragma unroll
    for (int qs = 0; qs < 4; ++qs)
#pragma unroll
        for (int kh = 0; kh < 2; ++kh)
            qf[qs][kh] = *(const s16x8*)(q + ((size_t)b * TT + qw0 + qs * 16 + l16) * QLD +
                                         h * DD + kh * 32 + quad * 8);

    f32x4 o[4][4];
    float lsum[4] = {0.f, 0.f, 0.f, 0.f};
#pragma unroll
    for (int qs = 0; qs < 4; ++qs)
#pragma unroll
        for (int nt = 0; nt < 4; ++nt) o[qs][nt] = (f32x4){0.f, 0.f, 0.f, 0.f};

    for (int kt = 0; kt <= qt; ++kt) {
        const int s0 = kt * 64;
        // ---- K fragments: A-operand of S^T = K*Q^T (row = key) ----
        s16x8 kf[4][2];
#pragma unroll
        for (int nt = 0; nt < 4; ++nt) {
            const unsigned short* kr = kb + (size_t)(s0 + nt * 16 + l16) * CC;
            kf[nt][0] = *(const s16x8*)(kr);
            kf[nt][1] = *(const s16x8*)(kr + 32);
        }
        // ---- V fragments: B-operand of PV (k = key, n = dv) ----
        s16x8 vf[4][2];
#pragma unroll
        for (int nt = 0; nt < 4; ++nt) {
            const unsigned short* vr = vb + (size_t)(nt * 16 + l16) * TT + s0;
            vf[nt][0] = *(const s16x8*)(vr);
            vf[nt][1] = *(const s16x8*)(vr + 32);
        }

        const bool diag = (kt == qt);  // only the diagonal tile is masked
#pragma unroll
        for (int qs = 0; qs < 4; ++qs) {
            // S^T: D row=key (quad*4+r within 16nt), col=q (l16)
            f32x4 st[4];
#pragma unroll
            for (int nt = 0; nt < 4; ++nt) {
                f32x4 a = (f32x4){0.f, 0.f, 0.f, 0.f};
                a = __builtin_amdgcn_mfma_f32_16x16x32_bf16(kf[nt][0], qf[qs][0], a, 0, 0, 0);
                a = __builtin_amdgcn_mfma_f32_16x16x32_bf16(kf[nt][1], qf[qs][1], a, 0, 0, 0);
                st[nt] = a;
            }
            const int qidx = qw0 + qs * 16 + l16;
            unsigned pc[4][2];
            float ts = 0.f;
#pragma unroll
            for (int nt = 0; nt < 4; ++nt) {
                const int key0 = s0 + nt * 16 + quad * 4;
                float p[4];
#pragma unroll
                for (int r = 0; r < 4; ++r) {
                    float sv = st[nt][r];
                    if (diag && (key0 + r > qidx)) sv = -1e30f;
                    p[r] = fast_exp2(sv);
                }
                ts += (p[0] + p[1]) + (p[2] + p[3]);
                pc[nt][0] = pack_bf16_trunc(p[0], p[1]);
                pc[nt][1] = pack_bf16_trunc(p[2], p[3]);
            }
            lsum[qs] += ts;
            // in-register P redistribution (verified r2): quads exchange via
            // permlane32/16 swaps -> pf[kh] = P[q=l16][key=kh*32+quad*8+j]
            s16x8 pf[2];
#pragma unroll
            for (int kh = 0; kh < 2; ++kh) {
                auto sa = __builtin_amdgcn_permlane32_swap(
                    (int)pc[2 * kh + 0][0], (int)pc[2 * kh + 1][0], false, false);
                auto w02 = __builtin_amdgcn_permlane16_swap(sa[0], sa[1], false, false);
                auto sb = __builtin_amdgcn_permlane32_swap(
                    (int)pc[2 * kh + 0][1], (int)pc[2 * kh + 1][1], false, false);
                auto w13 = __builtin_amdgcn_permlane16_swap(sb[0], sb[1], false, false);
                union { unsigned u[4]; s16x8 v; } fu;
                fu.u[0] = (unsigned)w02[0];  // keys +0,+1
                fu.u[1] = (unsigned)w13[0];  // keys +2,+3
                fu.u[2] = (unsigned)w02[1];  // keys +4,+5
                fu.u[3] = (unsigned)w13[1];  // keys +6,+7
                pf[kh] = fu.v;
            }
            // PV: o row=q (quad*4+r within 16), col=dv (l16)
#pragma unroll
            for (int nt = 0; nt < 4; ++nt) {
                o[qs][nt] = __builtin_amdgcn_mfma_f32_16x16x32_bf16(pf[0], vf[nt][0],
                                                                    o[qs][nt], 0, 0, 0);
                o[qs][nt] = __builtin_amdgcn_mfma_f32_16x16x32_bf16(pf[1], vf[nt][1],
                                                                    o[qs][nt], 0, 0, 0);
            }
        }
    }

    // final l reduction: quads hold partial sums for query qs*16+l16
    float lfull[4];
#pragma unroll
    for (int qs = 0; qs < 4; ++qs) {
        float s = lsum[qs];
        s += __shfl_xor(s, 16);
        s += __shfl_xor(s, 32);
        lfull[qs] = s;
    }

    // store: o element = (query qs*16+quad*4+r, dv nt*16+l16)
#pragma unroll
    for (int qs = 0; qs < 4; ++qs) {
#pragma unroll
        for (int r = 0; r < 4; ++r) {
            const float inv = 1.f / __shfl(lfull[qs], quad * 4 + r);
            unsigned short* yb = y + ((size_t)b * TT + qw0 + qs * 16 + quad * 4 + r) * CC +
                                 h * DD + l16;
#pragma unroll
            for (int nt = 0; nt < 4; ++nt)
                yb[nt * 16] = f2bf(o[qs][nt][r] * inv);
        }
    }
}

extern "C" void kernel_launch(void* const* d_in, const int* in_sizes, int n_in,
                              void* d_out, int out_size, void* d_ws, size_t ws_size,
                              hipStream_t stream) {
    const float* x   = (const float*)d_in[0];
    const float* Wq  = (const float*)d_in[1];
    const float* Wkv = (const float*)d_in[2];
    const float* Wk  = (const float*)d_in[3];
    const float* Wv  = (const float*)d_in[4];
    const float* Wo  = (const float*)d_in[5];
    float* out = (float*)d_out;

    const int M = BB * TT;  // 8192
    unsigned short* p = (unsigned short*)d_ws;
    unsigned short* xb    = p; p += (size_t)M * CC;     // bf16 x
    unsigned short* qlatb = p; p += (size_t)M * QLD;    // fused q | latent
    unsigned short* kb    = p; p += (size_t)M * CC;
    unsigned short* vtb   = p; p += (size_t)M * CC;
    unsigned short* yb    = p; p += (size_t)M * CC;
    unsigned short* W1t   = p; p += (size_t)QLD * CC;   // [Wq^T ; Wkv^T]  [1280][1024]
    unsigned short* W2t   = p; p += (size_t)(2 * CC) * LL;  // [Wk^T ; Wv^T] [2048][256]
    unsigned short* Wot   = p; p += (size_t)CC * CC;

    const float qscale = 0.125f * 1.44269504f;  // 1/sqrt(64) * log2(e), folded into Wq

    fused_cvt<<<8896, 256, 0, stream>>>(x, xb, Wq, Wkv, Wk, Wv, Wo,
                                        W1t, W2t, Wot, qscale);
    // fused q|latent projection: [M,1280] = x @ [Wq | Wkv]
    bgemm<1><<<dim3(QLD / 128, M / 128), 256, 0, stream>>>(
        xb, W1t, qlatb, nullptr, M, QLD, CC, CC, QLD);
    // fused k|v up-projection: k half -> kb, v half -> vtb (transposed)
    bgemm<3><<<dim3(2 * CC / 128, M / 128), 256, 0, stream>>>(
        qlatb + CC, W2t, kb, vtb, M, 2 * CC, LL, QLD, CC);
    mla_attn3<<<dim3(BB * HH, TT / 64), 64, 0, stream>>>(qlatb, kb, vtb, yb);
    bgemm<0><<<dim3(CC / 128, M / 128), 256, 0, stream>>>(
        yb, Wot, out, nullptr, M, CC, CC, CC, CC);
}

// Round 5
// 225.601 us; speedup vs baseline: 1.1026x; 1.0871x over previous
//
#include <hip/hip_runtime.h>
#include <cstddef>
#include <cstdint>

#define BB 4
#define TT 2048
#define CC 1024
#define LL 256
#define HH 16
#define DD 64   // head size
#define QLD (CC + LL)  // 1280: row stride of fused q|latent buffer

typedef __attribute__((ext_vector_type(8))) short s16x8;
typedef __attribute__((ext_vector_type(4))) float f32x4;

static __device__ inline unsigned short f2bf(float f) {
    union { float f; unsigned u; } v; v.f = f;
    unsigned r = v.u + 0x7fffu + ((v.u >> 16) & 1u);  // RNE
    return (unsigned short)(r >> 16);
}

static __device__ inline float fast_exp2(float x) {
#if __has_builtin(__builtin_amdgcn_exp2f)
    return __builtin_amdgcn_exp2f(x);
#else
    return exp2f(x);
#endif
}

// pack two f32 -> two bf16 (truncation) in one v_perm_b32; lo -> low 16 bits
static __device__ inline unsigned pack_bf16_trunc(float lo, float hi) {
    union { float f; unsigned u; } a, b;
    a.f = lo; b.f = hi;
    return __builtin_amdgcn_perm(b.u, a.u, 0x07060302u);
}

// async global->LDS, 16B per lane; LDS dest = wave-uniform base + lane*16
#define GLDS16(g, l)                                             \
    __builtin_amdgcn_global_load_lds(                            \
        (__attribute__((address_space(1))) void*)(g),            \
        (__attribute__((address_space(3))) void*)(l), 16, 0, 0)

// ====================== fused conversion kernel =============================
// blocks [0, 8192): x fp32 -> bf16 (1024 elems/block)
// blocks [8192, 8896): one 64x64 transpose tile of a weight matrix
extern "C" __global__ __launch_bounds__(256)
void fused_cvt(const float* __restrict__ x, unsigned short* __restrict__ xb,
               const float* __restrict__ Wq, const float* __restrict__ Wkv,
               const float* __restrict__ Wk, const float* __restrict__ Wv,
               const float* __restrict__ Wo,
               unsigned short* __restrict__ W1t, unsigned short* __restrict__ W2t,
               unsigned short* __restrict__ Wot, float qscale) {
    __shared__ unsigned short Ts[64][72];
    const int t = threadIdx.x;
    int blk = blockIdx.x;
    if (blk < 8192) {
        const int i = blk * 256 + t;
        const float4 v = ((const float4*)x)[i];
        ushort4 o;
        o.x = f2bf(v.x); o.y = f2bf(v.y); o.z = f2bf(v.z); o.w = f2bf(v.w);
        ((ushort4*)xb)[i] = o;
        return;
    }
    blk -= 8192;
    const float* W; unsigned short* Wt; int K, N; float scale; int tile;
    if (blk < 256)      { W = Wq;  Wt = W1t;                      K = CC; N = CC; scale = qscale; tile = blk; }
    else if (blk < 320) { W = Wkv; Wt = W1t + (size_t)CC * CC;    K = CC; N = LL; scale = 1.f;    tile = blk - 256; }
    else if (blk < 384) { W = Wk;  Wt = W2t;                      K = LL; N = CC; scale = 1.f;    tile = blk - 320; }
    else if (blk < 448) { W = Wv;  Wt = W2t + (size_t)CC * LL;    K = LL; N = CC; scale = 1.f;    tile = blk - 384; }
    else                { W = Wo;  Wt = Wot;                      K = CC; N = CC; scale = 1.f;    tile = blk - 448; }
    const int ktiles = K >> 6;
    const int k0 = (tile % ktiles) * 64, n0 = (tile / ktiles) * 64;
#pragma unroll
    for (int l = 0; l < 4; ++l) {
        const int idx = t + l * 256;
        const int r = idx >> 4, c4 = (idx & 15) * 4;
        const float4 v = *(const float4*)(W + (size_t)(k0 + r) * N + n0 + c4);
        Ts[c4 + 0][r] = f2bf(v.x * scale); Ts[c4 + 1][r] = f2bf(v.y * scale);
        Ts[c4 + 2][r] = f2bf(v.z * scale); Ts[c4 + 3][r] = f2bf(v.w * scale);
    }
    __syncthreads();
#pragma unroll
    for (int l = 0; l < 2; ++l) {
        const int idx = t + l * 256;
        const int n = idx >> 3, seg = idx & 7;
        *(s16x8*)(Wt + (size_t)(n0 + n) * K + k0 + seg * 8) = *(const s16x8*)&Ts[n][seg * 8];
    }
}

// ========== bf16 MFMA GEMM: C[M,N] = A[M,K] @ Bt[N,K]^T ====================
// 128x128 tile, BK=64, 256 threads = 4 waves (2x2), 4x4 16x16x32 MFMA per wave.
// Staging via global_load_lds with XOR source swizzle: LDS[row][s] holds global
// segment s^(row&7)  ->  fragment ds_read_b128 is 2-way banked (free, m136).
// Round 5: bijective XCD-aware block swizzle (T1) — consecutive tiles of the
// same A-panel land on the same XCD's L2 (all grids are %8==0).
// MODE 0: fp32 store (ldc) | MODE 1: bf16 store (ldc)
// MODE 3: cols < CC -> bf16 store (ldc); cols >= CC -> transposed vt store
template <int MODE>
__global__ __launch_bounds__(256)
void bgemm(const unsigned short* __restrict__ A, const unsigned short* __restrict__ Bt,
           void* __restrict__ Cv, void* __restrict__ Cv2,
           int M, int N, int K, int lda, int ldc) {
    __shared__ unsigned short As[128][64];
    __shared__ unsigned short Bs[128][64];
    const int t = threadIdx.x;
    const int w = t >> 6, lane = t & 63, quad = lane >> 4, l16 = lane & 15;
    const int wm = w & 1, wn = w >> 1;

    // XCD-aware swizzle: wg -> (wg%8)*(nwg/8) + wg/8 (bijective when nwg%8==0)
    int wg = blockIdx.y * gridDim.x + blockIdx.x;
    const int nwg = gridDim.x * gridDim.y;
    if ((nwg & 7) == 0) wg = (wg & 7) * (nwg >> 3) + (wg >> 3);
    const int bx = wg % gridDim.x, by = wg / gridDim.x;
    const int row0 = by * 128, col0 = bx * 128;

    const int sr = lane >> 3;                 // row within an 8-row chunk
    const int sc = ((lane & 7) ^ sr) * 8;     // swizzled 16B source segment

    f32x4 acc[4][4];
#pragma unroll
    for (int i = 0; i < 4; ++i)
#pragma unroll
        for (int j = 0; j < 4; ++j) acc[i][j] = (f32x4){0.f, 0.f, 0.f, 0.f};

    const unsigned short* Ab = A + (size_t)(row0 + w * 32 + sr) * lda + sc;
    const unsigned short* Bb = Bt + (size_t)(col0 + w * 32 + sr) * K + sc;

    for (int k0 = 0; k0 < K; k0 += 64) {
#pragma unroll
        for (int c = 0; c < 4; ++c) {
            GLDS16(Ab + (size_t)(c * 8) * lda + k0, &As[w * 32 + c * 8][0]);
            GLDS16(Bb + (size_t)(c * 8) * K + k0, &Bs[w * 32 + c * 8][0]);
        }
        __syncthreads();
#pragma unroll
        for (int kk = 0; kk < 2; ++kk) {
            s16x8 af[4], bfr[4];
#pragma unroll
            for (int mt = 0; mt < 4; ++mt)
                af[mt] = *(const s16x8*)
                    &As[wm * 64 + mt * 16 + l16][((kk * 4 + quad) ^ (l16 & 7)) * 8];
#pragma unroll
            for (int nt = 0; nt < 4; ++nt)
                bfr[nt] = *(const s16x8*)
                    &Bs[wn * 64 + nt * 16 + l16][((kk * 4 + quad) ^ (l16 & 7)) * 8];
#pragma unroll
            for (int mt = 0; mt < 4; ++mt)
#pragma unroll
                for (int nt = 0; nt < 4; ++nt)
                    acc[mt][nt] = __builtin_amdgcn_mfma_f32_16x16x32_bf16(
                        af[mt], bfr[nt], acc[mt][nt], 0, 0, 0);
        }
        __syncthreads();
    }

    if constexpr (MODE == 0) {
        float* C = (float*)Cv;
#pragma unroll
        for (int mt = 0; mt < 4; ++mt)
#pragma unroll
            for (int nt = 0; nt < 4; ++nt)
#pragma unroll
                for (int r = 0; r < 4; ++r)
                    C[(size_t)(row0 + wm * 64 + mt * 16 + quad * 4 + r) * ldc +
                      col0 + wn * 64 + nt * 16 + l16] = acc[mt][nt][r];
    } else if constexpr (MODE == 1) {
        unsigned short* C = (unsigned short*)Cv;
#pragma unroll
        for (int mt = 0; mt < 4; ++mt)
#pragma unroll
            for (int nt = 0; nt < 4; ++nt)
#pragma unroll
                for (int r = 0; r < 4; ++r)
                    C[(size_t)(row0 + wm * 64 + mt * 16 + quad * 4 + r) * ldc +
                      col0 + wn * 64 + nt * 16 + l16] = f2bf(acc[mt][nt][r]);
    } else {
        if (col0 < CC) {
            unsigned short* C = (unsigned short*)Cv;
#pragma unroll
            for (int mt = 0; mt < 4; ++mt)
#pragma unroll
                for (int nt = 0; nt < 4; ++nt)
#pragma unroll
                    for (int r = 0; r < 4; ++r)
                        C[(size_t)(row0 + wm * 64 + mt * 16 + quad * 4 + r) * ldc +
                          col0 + wn * 64 + nt * 16 + l16] = f2bf(acc[mt][nt][r]);
        } else {
            // v-half: transposed store vt[b][h][dv][t]
            __shared__ unsigned short Tb[64][136];
            unsigned short* vt = (unsigned short*)Cv2;
            const int b   = row0 >> 11;  // 2048 tokens per batch; tile never crosses
            const int tl0 = row0 & 2047;
#pragma unroll
            for (int h = 0; h < 2; ++h) {
                if (wn == h) {
#pragma unroll
                    for (int mt = 0; mt < 4; ++mt)
#pragma unroll
                        for (int nt = 0; nt < 4; ++nt)
#pragma unroll
                            for (int r = 0; r < 4; ++r)
                                Tb[nt * 16 + l16][wm * 64 + mt * 16 + quad * 4 + r] =
                                    f2bf(acc[mt][nt][r]);
                }
                __syncthreads();
                const int head = ((col0 - CC) >> 6) + h;
#pragma unroll
                for (int l = 0; l < 4; ++l) {
                    const int idx = t + l * 256;
                    const int dv = idx >> 4, seg = idx & 15;
                    *(s16x8*)(vt + (((size_t)b * HH + head) * DD + dv) * TT + tl0 + seg * 8) =
                        *(const s16x8*)&Tb[dv][seg * 8];
                }
                __syncthreads();
            }
        }
    }
}

// ================= Flash attention v2 (r2 structure) + phase stagger ========
// grid (B*H, TT/128) with qt2 REVERSED (heaviest blocks dispatch first).
// 256 threads = 4 waves; wave w owns 32 queries. P fully in registers
// (permlane redistribution, verified r2). K/V double-buffered.
//
// Round 5 change: DE-CONVOY. All blocks run identical barrier-periodic code
// and launch simultaneously -> co-resident blocks' vmcnt(0)+barrier drains
// stay time-aligned forever (chip-wide dead time each phase; explains r1/r2
// nulls and r3 regression). A one-time per-block s_sleep stagger ({0..3} x
// ~1.5K cyc, 2-bit hash) anti-aligns phases so one block's drain overlaps
// another's compute. Zero correctness impact.
extern "C" __global__ __launch_bounds__(256, 4)
void mla_attn2(const unsigned short* __restrict__ q,
               const unsigned short* __restrict__ k,
               const unsigned short* __restrict__ vt,
               unsigned short* __restrict__ y) {
    __shared__ unsigned short Ks[2][64][64];  // [buf][key][d], source-XOR-swizzled segs
    __shared__ unsigned short Vs[2][64][64];  // [buf][dv][key], source-XOR-swizzled segs

    // phase stagger (wave-uniform, one-time)
    {
        const unsigned bid = blockIdx.y * gridDim.x + blockIdx.x;
        const unsigned stag = (bid * 0x9E3779B1u) >> 30;  // 2 well-mixed bits
        for (unsigned i = 0; i < stag; ++i) __builtin_amdgcn_s_sleep(23);
    }

    const int bh = blockIdx.x;
    const int qt2 = (gridDim.y - 1) - blockIdx.y;  // big blocks first (LPT packing)
    const int b = bh >> 4, h = bh & 15;
    const int t0 = qt2 * 128;
    const int t = threadIdx.x;
    const int w = t >> 6, lane = t & 63, quad = lane >> 4, l16 = lane & 15;
    const int qw0 = t0 + w * 32;                       // wave's first query
    const int swz = ((lane & 7) ^ ((lane >> 3) & 7)) * 8;  // swizzled source seg
    const int lrow = lane >> 3;                        // row within 8-row chunk

    const unsigned short* kb0 = k + ((size_t)b * TT) * CC + h * DD;
    const unsigned short* vb0 = vt + ((size_t)(b * HH + h)) * DD * TT;

    // Q fragments straight from global (pre-scaled), hoisted
    s16x8 qf[2][2];
#pragma unroll
    for (int qs = 0; qs < 2; ++qs)
#pragma unroll
        for (int kh = 0; kh < 2; ++kh)
            qf[qs][kh] = *(const s16x8*)(q + ((size_t)b * TT + qw0 + qs * 16 + l16) * QLD +
                                         h * DD + kh * 32 + quad * 8);

    f32x4 o[2][4];
    float lsum[2] = {0.f, 0.f};
#pragma unroll
    for (int qs = 0; qs < 2; ++qs)
#pragma unroll
        for (int nt = 0; nt < 4; ++nt) o[qs][nt] = (f32x4){0.f, 0.f, 0.f, 0.f};

    const int nkt = 2 * qt2 + 2;

    // stage K,V tiles into buffer bi_: wave w covers chunks g=w*2..w*2+1 (8 rows each)
#define STAGE_KV(kt_, bi_)                                                     \
    do {                                                                       \
        const int s0_ = (kt_) * 64;                                            \
        _Pragma("unroll")                                                      \
        for (int c = 0; c < 2; ++c) {                                          \
            const int g = w * 2 + c;                                           \
            const int row = g * 8 + lrow;                                      \
            GLDS16(kb0 + (size_t)(s0_ + row) * CC + swz, &Ks[bi_][g * 8][0]);  \
            GLDS16(vb0 + (size_t)row * TT + s0_ + swz, &Vs[bi_][g * 8][0]);    \
        }                                                                      \
    } while (0)

    STAGE_KV(0, 0);
    __syncthreads();  // compiler emits vmcnt(0) before the barrier -> buf0 ready

    for (int kt = 0; kt < nkt; ++kt) {
        const int cur = kt & 1;
        // prefetch next tile into the buffer everyone just finished reading
        if (kt + 1 < nkt) STAGE_KV(kt + 1, cur ^ 1);

        const int s0 = kt * 64;
        if (s0 <= qw0 + 31) {  // wave-uniform: any unmasked element?
            const unsigned short (*Kc)[64] = Ks[cur];
            const unsigned short (*Vc)[64] = Vs[cur];
            // S^T = K Q^T : A=K[m=key], B=Q^T[k=d][n=q]; D row=key, col=q
            f32x4 st[2][4];
#pragma unroll
            for (int nt = 0; nt < 4; ++nt) {
                const int key = nt * 16 + l16;
                const s16x8 kf0 = *(const s16x8*)&Kc[key][((0 + quad) ^ (l16 & 7)) * 8];
                const s16x8 kf1 = *(const s16x8*)&Kc[key][((4 + quad) ^ (l16 & 7)) * 8];
#pragma unroll
                for (int qs = 0; qs < 2; ++qs) {
                    f32x4 acc = (f32x4){0.f, 0.f, 0.f, 0.f};
                    acc = __builtin_amdgcn_mfma_f32_16x16x32_bf16(kf0, qf[qs][0], acc, 0, 0, 0);
                    acc = __builtin_amdgcn_mfma_f32_16x16x32_bf16(kf1, qf[qs][1], acc, 0, 0, 0);
                    st[qs][nt] = acc;
                }
            }

            const bool maskedTile = (s0 + 63 > qw0);  // wave-uniform
            s16x8 pf[2][2];
#pragma unroll
            for (int qs = 0; qs < 2; ++qs) {
                const int qidx = qw0 + qs * 16 + l16;
                unsigned pc[4][2];
                float tsum = 0.f;
#pragma unroll
                for (int nt = 0; nt < 4; ++nt) {
                    const int key0 = s0 + nt * 16 + quad * 4;
                    float p[4];
#pragma unroll
                    for (int r = 0; r < 4; ++r) {
                        float sv = st[qs][nt][r];
                        if (maskedTile && (key0 + r > qidx)) sv = -1e30f;
                        p[r] = fast_exp2(sv);
                    }
                    tsum += (p[0] + p[1]) + (p[2] + p[3]);  // tree, short dep chain
                    pc[nt][0] = pack_bf16_trunc(p[0], p[1]);
                    pc[nt][1] = pack_bf16_trunc(p[2], p[3]);
                }
                lsum[qs] += tsum;
                // in-register P redistribution: quads exchange via permlane swaps
#pragma unroll
                for (int kh = 0; kh < 2; ++kh) {
                    auto s0a = __builtin_amdgcn_permlane32_swap(
                        (int)pc[2 * kh + 0][0], (int)pc[2 * kh + 1][0], false, false);
                    auto w02 = __builtin_amdgcn_permlane16_swap(s0a[0], s0a[1], false, false);
                    auto s1a = __builtin_amdgcn_permlane32_swap(
                        (int)pc[2 * kh + 0][1], (int)pc[2 * kh + 1][1], false, false);
                    auto w13 = __builtin_amdgcn_permlane16_swap(s1a[0], s1a[1], false, false);
                    union { unsigned u[4]; s16x8 v; } fu;
                    fu.u[0] = (unsigned)w02[0];  // keys +0,+1
                    fu.u[1] = (unsigned)w13[0];  // keys +2,+3
                    fu.u[2] = (unsigned)w02[1];  // keys +4,+5
                    fu.u[3] = (unsigned)w13[1];  // keys +6,+7
                    pf[qs][kh] = fu.v;
                }
            }

            // PV: A=P[m=q][k=key] in registers; B=V[k=key][n=dv] from Vs rows
#pragma unroll
            for (int nt = 0; nt < 4; ++nt) {
                const int dv = nt * 16 + l16;
                const s16x8 vf0 = *(const s16x8*)&Vc[dv][((0 + quad) ^ (l16 & 7)) * 8];
                const s16x8 vf1 = *(const s16x8*)&Vc[dv][((4 + quad) ^ (l16 & 7)) * 8];
#pragma unroll
                for (int qs = 0; qs < 2; ++qs) {
                    o[qs][nt] = __builtin_amdgcn_mfma_f32_16x16x32_bf16(pf[qs][0], vf0,
                                                                        o[qs][nt], 0, 0, 0);
                    o[qs][nt] = __builtin_amdgcn_mfma_f32_16x16x32_bf16(pf[qs][1], vf1,
                                                                        o[qs][nt], 0, 0, 0);
                }
            }
        }
        // single barrier per tile: all waves done reading buf[cur] AND
        // (via the implicit vmcnt(0) drain) tile kt+1 fully landed in buf[cur^1]
        __syncthreads();
    }

    // final l reduction: quads hold partial sums for query qs*16+l16
    float lfull[2];
#pragma unroll
    for (int qs = 0; qs < 2; ++qs) {
        float s = lsum[qs];
        s += __shfl_xor(s, 16);
        s += __shfl_xor(s, 32);
        lfull[qs] = s;
    }

    // store: o element = (query qs*16+quad*4+r, dv nt*16+l16)
#pragma unroll
    for (int qs = 0; qs < 2; ++qs) {
#pragma unroll
        for (int r = 0; r < 4; ++r) {
            const float inv = 1.f / __shfl(lfull[qs], quad * 4 + r);
            unsigned short* yb = y + ((size_t)b * TT + qw0 + qs * 16 + quad * 4 + r) * CC +
                                 h * DD + l16;
#pragma unroll
            for (int nt = 0; nt < 4; ++nt)
                yb[nt * 16] = f2bf(o[qs][nt][r] * inv);
        }
    }
}

extern "C" void kernel_launch(void* const* d_in, const int* in_sizes, int n_in,
                              void* d_out, int out_size, void* d_ws, size_t ws_size,
                              hipStream_t stream) {
    const float* x   = (const float*)d_in[0];
    const float* Wq  = (const float*)d_in[1];
    const float* Wkv = (const float*)d_in[2];
    const float* Wk  = (const float*)d_in[3];
    const float* Wv  = (const float*)d_in[4];
    const float* Wo  = (const float*)d_in[5];
    float* out = (float*)d_out;

    const int M = BB * TT;  // 8192
    unsigned short* p = (unsigned short*)d_ws;
    unsigned short* xb    = p; p += (size_t)M * CC;     // bf16 x
    unsigned short* qlatb = p; p += (size_t)M * QLD;    // fused q | latent
    unsigned short* kb    = p; p += (size_t)M * CC;
    unsigned short* vtb   = p; p += (size_t)M * CC;
    unsigned short* yb    = p; p += (size_t)M * CC;
    unsigned short* W1t   = p; p += (size_t)QLD * CC;   // [Wq^T ; Wkv^T]  [1280][1024]
    unsigned short* W2t   = p; p += (size_t)(2 * CC) * LL;  // [Wk^T ; Wv^T] [2048][256]
    unsigned short* Wot   = p; p += (size_t)CC * CC;

    const float qscale = 0.125f * 1.44269504f;  // 1/sqrt(64) * log2(e), folded into Wq

    fused_cvt<<<8896, 256, 0, stream>>>(x, xb, Wq, Wkv, Wk, Wv, Wo,
                                        W1t, W2t, Wot, qscale);
    // fused q|latent projection: [M,1280] = x @ [Wq | Wkv]
    bgemm<1><<<dim3(QLD / 128, M / 128), 256, 0, stream>>>(
        xb, W1t, qlatb, nullptr, M, QLD, CC, CC, QLD);
    // fused k|v up-projection: k half -> kb, v half -> vtb (transposed)
    bgemm<3><<<dim3(2 * CC / 128, M / 128), 256, 0, stream>>>(
        qlatb + CC, W2t, kb, vtb, M, 2 * CC, LL, QLD, CC);
    mla_attn2<<<dim3(BB * HH, TT / 128), 256, 0, stream>>>(qlatb, kb, vtb, yb);
    bgemm<0><<<dim3(CC / 128, M / 128), 256, 0, stream>>>(
        yb, Wot, out, nullptr, M, CC, CC, CC, CC);
}